// Round 10
// baseline (173.480 us; speedup 1.0000x reference)
//
#include <hip/hip_runtime.h>

#define N_NODES 50000
#define N_EDGES 800000
#define DIM 128
#define NCHUNK 3125     // N_NODES / 16
#define SCAN_B 49       // ceil(50000 / 1024)
#define NBINS 782       // ceil(50000 / 64)
#define EPB 8192        // edges per binscat block
#define NSCAT 98        // ceil(800000 / 8192)
#define ZERO_INTS 50816 // 203,264 bytes / 4

typedef _Float16 f16;
typedef _Float16 f16x4 __attribute__((ext_vector_type(4)));
typedef _Float16 f16x8 __attribute__((ext_vector_type(8)));
typedef float    f32x4 __attribute__((ext_vector_type(4)));
typedef float    f32x8 __attribute__((ext_vector_type(8)));

__device__ inline f32x8 cvt8(f16x8 v) { return __builtin_convertvector(v, f32x8); }

__device__ inline int bucketof(int d) {
    if (d < 10) return 0;
    if (d < 13) return 1;
    if (d < 16) return 2;
    if (d < 19) return 3;
    if (d < 22) return 4;
    if (d < 26) return 5;
    if (d < 32) return 6;
    return 7;
}

// ---------------- zero the counter region (replaces 41us runtime fill kernel) ----------------

__global__ __launch_bounds__(256) void k_zero(int* __restrict__ p) {
    int i = blockIdx.x * 256 + threadIdx.x;
    if (i < ZERO_INTS) p[i] = 0;
}

// ---------------- fused: edge count (even blocks) + x->f16 (odd blocks) + W prep (tail blocks) ----------------

__global__ __launch_bounds__(256) void k_prep(const int* __restrict__ dst, int* __restrict__ deg,
                                              const float* __restrict__ x, f16* __restrict__ xh,
                                              const float* __restrict__ W1l, const float* __restrict__ W1r,
                                              const float* __restrict__ W2l, const float* __restrict__ W2r,
                                              f16* __restrict__ Wf1, f16* __restrict__ Wf2) {
    int b = blockIdx.x;
    if (b < 6250) {
        int idx = (b >> 1) * 256 + threadIdx.x;      // 0..799,999 exactly
        if ((b & 1) == 0) {
            atomicAdd(&deg[dst[idx]], 1);
        } else {
            const float4* xs = (const float4*)x;
            float4 v0 = xs[(size_t)idx * 2];
            float4 v1 = xs[(size_t)idx * 2 + 1];
            f16x8 o;
            o[0]=(f16)v0.x; o[1]=(f16)v0.y; o[2]=(f16)v0.z; o[3]=(f16)v0.w;
            o[4]=(f16)v1.x; o[5]=(f16)v1.y; o[6]=(f16)v1.z; o[7]=(f16)v1.w;
            *(f16x8*)(xh + (size_t)idx * 8) = o;
        }
    } else {
        int t = (b - 6250) * 256 + threadIdx.x;      // 0..8191
        int layer = t >> 12;
        int nt = (t >> 9) & 7;
        int kk = (t >> 6) & 7;
        int lane = t & 63;
        int r = lane & 15, g = lane >> 4;
        int n = nt * 16 + r;
        const float* Wl_ = layer ? W2l : W1l;
        const float* Wr_ = layer ? W2r : W1r;
        f16x8 frag;
#pragma unroll
        for (int j = 0; j < 8; ++j) {
            int k = kk * 32 + g * 4 + (j & 3) + ((j >> 2) << 4);
            float f = (k < 128) ? Wl_[n * 128 + k] : Wr_[n * 128 + (k - 128)];
            frag[j] = (f16)f;
        }
        f16* dstp = (layer ? Wf2 : Wf1) + ((size_t)((nt * 8 + kk) * 64 + lane)) * 8;
        *(f16x8*)dstp = frag;
    }
}

// ---------------- scan phase A: block-local exclusive scan + block sums + degree histogram ----------------

__global__ __launch_bounds__(1024) void k_scanA(const int* __restrict__ deg, int* __restrict__ rowptr,
                                                int* __restrict__ bsum, int* __restrict__ bcnt) {
    __shared__ int sm[1024];
    __shared__ int h[8];
    int t = threadIdx.x;
    if (t < 8) h[t] = 0;
    int i = blockIdx.x * 1024 + t;
    int v = (i < N_NODES) ? deg[i] : 0;
    int orig = v;
    sm[t] = v;
    __syncthreads();
    if (i < N_NODES) atomicAdd(&h[bucketof(orig)], 1);
    for (int off = 1; off < 1024; off <<= 1) {
        int u = (t >= off) ? sm[t - off] : 0;
        __syncthreads();
        sm[t] += u;
        __syncthreads();
    }
    if (i < N_NODES) rowptr[i] = sm[t] - orig;
    if (t == 1023) bsum[blockIdx.x] = sm[t];
    if (t < 8 && h[t] > 0) atomicAdd(&bcnt[t], h[t]);
}

// ---------------- scan phase B: scan 49 block sums + 8 bucket counts ----------------

__global__ __launch_bounds__(64) void k_scanB(const int* __restrict__ bsum, int* __restrict__ boff,
                                              int* __restrict__ rowptr, const int* __restrict__ bcnt,
                                              int* __restrict__ bbase) {
    int t = threadIdx.x;
    int orig = (t < SCAN_B) ? bsum[t] : 0;
    int v = orig;
    for (int off = 1; off < 64; off <<= 1) {
        int u = __shfl_up(v, off);
        if (t >= off) v += u;
    }
    if (t < SCAN_B) boff[t] = v - orig;
    if (t == 63) rowptr[N_NODES] = N_EDGES;
    if (t == 0) {
        int r = 0;
#pragma unroll
        for (int b = 0; b < 8; ++b) { bbase[b] = r; r += bcnt[b]; }
    }
}

// ---------------- scan phase C: finalize rowptr + bucket-major order (LDS histogram) ----------------

__global__ __launch_bounds__(1024) void k_scanC(int* __restrict__ rowptr, const int* __restrict__ boff,
                                                const int* __restrict__ deg, const int* __restrict__ bbase,
                                                int* __restrict__ bcnt2, int* __restrict__ order) {
    __shared__ int h[8];
    __shared__ int hb[8];
    int t = threadIdx.x;
    if (t < 8) h[t] = 0;
    __syncthreads();
    int i = blockIdx.x * 1024 + t;
    int b = 0, rank = 0;
    bool act = (i < N_NODES);
    if (act) {
        rowptr[i] += boff[blockIdx.x];
        b = bucketof(deg[i]);
        rank = atomicAdd(&h[b], 1);
    }
    __syncthreads();
    if (t < 8) hb[t] = atomicAdd(&bcnt2[t], h[t]);
    __syncthreads();
    if (act) order[bbase[b] + hb[b] + rank] = i;
}

// ---------------- binned scatter pass A: block-aggregated LDS histogram, packed (src<<6|d&63) ----------------

__global__ __launch_bounds__(1024) void k_binscat(const int* __restrict__ src, const int* __restrict__ dst,
                                                  const int* __restrict__ rowptr, int* __restrict__ binfill,
                                                  int* __restrict__ pairs) {
    __shared__ int hist[NBINS];
    __shared__ int base[NBINS];
    int t = threadIdx.x;
    for (int i = t; i < NBINS; i += 1024) hist[i] = 0;
    __syncthreads();
    int e0 = blockIdx.x * EPB;
    int mybin[8], myrank[8], mypack[8];
#pragma unroll
    for (int j = 0; j < 8; ++j) {
        int e = e0 + j * 1024 + t;
        if (e < N_EDGES) {
            int d = dst[e];
            int bin = d >> 6;
            mybin[j] = bin;
            mypack[j] = (src[e] << 6) | (d & 63);
            myrank[j] = atomicAdd(&hist[bin], 1);
        } else {
            mybin[j] = -1;
        }
    }
    __syncthreads();
    for (int i = t; i < NBINS; i += 1024) base[i] = atomicAdd(&binfill[i], hist[i]);
    __syncthreads();
#pragma unroll
    for (int j = 0; j < 8; ++j) {
        if (mybin[j] >= 0) {
            int bin = mybin[j];
            pairs[rowptr[bin << 6] + base[bin] + myrank[j]] = mypack[j];
        }
    }
}

// ---------------- binned scatter pass B: bin-local LDS counters -> final srt ----------------

__global__ __launch_bounds__(256) void k_binsolve(const int* __restrict__ pairs, const int* __restrict__ rowptr,
                                                  int* __restrict__ srt) {
    __shared__ int lfill[64];
    int bin = blockIdx.x;
    int nstart = bin << 6;
    int nend = min(N_NODES, nstart + 64);
    int t = threadIdx.x;
    if (t < 64) lfill[t] = (nstart + t < N_NODES) ? rowptr[nstart + t] : 0;
    __syncthreads();
    int estart = rowptr[nstart];
    int eend = rowptr[nend];
    for (int i = estart + t; i < eend; i += 256) {
        int p = pairs[i];
        int slot = atomicAdd(&lfill[p & 63], 1);
        srt[slot] = p >> 6;
    }
}

// ---------------- mean aggregation: 16-lane group per node, degree-binned order, unroll 4 ----------------

__global__ __launch_bounds__(256) void k_aggregate(const f16* __restrict__ X, const int* __restrict__ rowptr,
                                                   const int* __restrict__ srt, const int* __restrict__ order,
                                                   f16* __restrict__ out) {
    int gid = (blockIdx.x * 256 + threadIdx.x) >> 4;
    if (gid >= N_NODES) return;
    int w = order[gid];
    int lane = threadIdx.x & 15;
    const f16* __restrict__ base = X + lane * 8;
    int beg = rowptr[w], end = rowptr[w + 1];
    f32x8 A0 = {0.f,0.f,0.f,0.f,0.f,0.f,0.f,0.f};
    f32x8 A1 = A0, A2 = A0, A3 = A0;
    int e = beg;
    for (; e + 4 <= end; e += 4) {
        int s0 = srt[e], s1 = srt[e + 1], s2 = srt[e + 2], s3 = srt[e + 3];
        A0 += cvt8(*(const f16x8*)(base + s0 * DIM));
        A1 += cvt8(*(const f16x8*)(base + s1 * DIM));
        A2 += cvt8(*(const f16x8*)(base + s2 * DIM));
        A3 += cvt8(*(const f16x8*)(base + s3 * DIM));
    }
    if (e < end)     A0 += cvt8(*(const f16x8*)(base + srt[e] * DIM));
    if (e + 1 < end) A1 += cvt8(*(const f16x8*)(base + srt[e + 1] * DIM));
    if (e + 2 < end) A2 += cvt8(*(const f16x8*)(base + srt[e + 2] * DIM));
    A0 = (A0 + A1) + (A2 + A3);
    float inv = 1.0f / fmaxf((float)(end - beg), 1.0f);
    f16x8 r;
#pragma unroll
    for (int j = 0; j < 8; ++j) r[j] = (f16)(A0[j] * inv);
    *(f16x8*)(out + (size_t)w * DIM + lane * 8) = r;
}

// ---------------- MFMA dual GEMM: C = relu([agg|self] @ Wcat^T + b) ----------------

__global__ __launch_bounds__(512) void k_gemm(const f16* __restrict__ Agg, const float* __restrict__ A2,
                                              const f16* __restrict__ Wf, const float* __restrict__ bias,
                                              float* __restrict__ C, f16* __restrict__ Cb) {
    __shared__ uint4 Bsm[4096];   // 64 KB: [nt][kk][lane] 16B fragments
    int t = threadIdx.x;
    const uint4* wsrc = (const uint4*)Wf;
#pragma unroll
    for (int i = 0; i < 8; ++i) Bsm[t + i * 512] = wsrc[t + i * 512];
    __syncthreads();

    int wave = t >> 6, lane = t & 63;
    int chunk = blockIdx.x * 8 + wave;
    if (chunk >= NCHUNK) return;
    int r = lane & 15, g = lane >> 4;
    size_t row = (size_t)chunk * 16 + r;

    f32x4 acc[8];
#pragma unroll
    for (int nt = 0; nt < 8; ++nt) acc[nt] = (f32x4){0.f, 0.f, 0.f, 0.f};

    const f16* arow = Agg + row * DIM;
#pragma unroll
    for (int kk = 0; kk < 4; ++kk) {
        f16x4 q0 = *(const f16x4*)(arow + kk * 32 + g * 4);
        f16x4 q1 = *(const f16x4*)(arow + kk * 32 + g * 4 + 16);
        f16x8 a = __builtin_shufflevector(q0, q1, 0, 1, 2, 3, 4, 5, 6, 7);
#pragma unroll
        for (int nt = 0; nt < 8; ++nt) {
            f16x8 b = *(const f16x8*)&Bsm[(nt * 8 + kk) * 64 + lane];
            acc[nt] = __builtin_amdgcn_mfma_f32_16x16x32_f16(a, b, acc[nt], 0, 0, 0);
        }
    }
    const float* xrow = A2 + row * DIM;
#pragma unroll
    for (int kk = 4; kk < 8; ++kk) {
        int kl = (kk - 4) * 32 + g * 4;
        float4 v0 = *(const float4*)(xrow + kl);
        float4 v1 = *(const float4*)(xrow + kl + 16);
        float f[8] = {v0.x, v0.y, v0.z, v0.w, v1.x, v1.y, v1.z, v1.w};
        f16x8 ah, al;
#pragma unroll
        for (int j = 0; j < 8; ++j) {
            f16 h = (f16)f[j];
            ah[j] = h;
            al[j] = (f16)(f[j] - (float)h);
        }
#pragma unroll
        for (int nt = 0; nt < 8; ++nt) {
            f16x8 b = *(const f16x8*)&Bsm[(nt * 8 + kk) * 64 + lane];
            acc[nt] = __builtin_amdgcn_mfma_f32_16x16x32_f16(ah, b, acc[nt], 0, 0, 0);
            acc[nt] = __builtin_amdgcn_mfma_f32_16x16x32_f16(al, b, acc[nt], 0, 0, 0);
        }
    }
    size_t rbase = (size_t)chunk * 16 + g * 4;
#pragma unroll
    for (int nt = 0; nt < 8; ++nt) {
        int colc = nt * 16 + r;
        float bv = bias[colc];
#pragma unroll
        for (int q = 0; q < 4; ++q) {
            float v = fmaxf(acc[nt][q] + bv, 0.f);
            size_t idx = (rbase + q) * DIM + colc;
            C[idx] = v;
            if (Cb) Cb[idx] = (f16)v;
        }
    }
}

// ---------------- launch ----------------

extern "C" void kernel_launch(void* const* d_in, const int* in_sizes, int n_in,
                              void* d_out, int out_size, void* d_ws, size_t ws_size,
                              hipStream_t stream) {
    const float* x   = (const float*)d_in[0];
    const int*   ei  = (const int*)d_in[1];
    const float* W1l = (const float*)d_in[2];
    const float* b1  = (const float*)d_in[3];
    const float* W1r = (const float*)d_in[4];
    const float* W2l = (const float*)d_in[5];
    const float* b2  = (const float*)d_in[6];
    const float* W2r = (const float*)d_in[7];
    float* out = (float*)d_out;

    const int* src = ei;
    const int* dst = ei + N_EDGES;

    char* ws = (char*)d_ws;
    int*  deg     = (int*)(ws + 0);              // 200,000 B
    int*  bcnt    = (int*)(ws + 200064);         // 32 B
    int*  bcnt2   = (int*)(ws + 200096);         // 32 B
    int*  binfill = (int*)(ws + 200128);         // 3,128 B   (k_zero covers through here)
    int*  rowptr  = (int*)(ws + 203264);         // 200,004 B
    int*  srt     = (int*)(ws + 403328);         // 3,200,000 B
    f16*  xh      = (f16*)(ws + 3603328);        // 12.8 MB (x f16, later h f16)
    f16*  aggh    = (f16*)(ws + 16403328);       // 12.8 MB
    int*  pairs   = (int*)(ws + 16403328);       // 3.2 MB (overlaps aggh; dead before agg runs)
    f16*  Wf1     = (f16*)(ws + 29203328);       // 64 KB frag-order
    f16*  Wf2     = Wf1 + 32768;                 // 64 KB
    int*  bsum    = (int*)(ws + 29334400);       // 256 B
    int*  boff    = (int*)(ws + 29334656);       // 256 B
    int*  bbase   = (int*)(ws + 29334912);       // 64 B
    int*  order   = (int*)(ws + 29334976);       // 200,000 B

    dim3 blk(256);
    k_zero<<<dim3((ZERO_INTS + 255) / 256), blk, 0, stream>>>((int*)ws);
    k_prep<<<dim3(6282), blk, 0, stream>>>(dst, deg, x, xh, W1l, W1r, W2l, W2r, Wf1, Wf2);
    k_scanA<<<dim3(SCAN_B), dim3(1024), 0, stream>>>(deg, rowptr, bsum, bcnt);
    k_scanB<<<dim3(1), dim3(64), 0, stream>>>(bsum, boff, rowptr, bcnt, bbase);
    k_scanC<<<dim3(SCAN_B), dim3(1024), 0, stream>>>(rowptr, boff, deg, bbase, bcnt2, order);
    k_binscat<<<dim3(NSCAT), dim3(1024), 0, stream>>>(src, dst, rowptr, binfill, pairs);
    k_binsolve<<<dim3(NBINS), blk, 0, stream>>>(pairs, rowptr, srt);

    dim3 grdA(NCHUNK);                 // 50000 groups x 16 lanes = 3125 blocks
    dim3 grdG((NCHUNK + 7) / 8);

    // layer 1: h (f32 -> d_out, f16 -> xh) = relu(agg1 @ W1l^T + b1 + x @ W1r^T)
    k_aggregate<<<grdA, blk, 0, stream>>>(xh, rowptr, srt, order, aggh);
    k_gemm<<<grdG, dim3(512), 0, stream>>>(aggh, x, Wf1, b1, out, xh);

    // layer 2: out = relu(agg2 @ W2l^T + b2 + h @ W2r^T)
    k_aggregate<<<grdA, blk, 0, stream>>>(xh, rowptr, srt, order, aggh);
    k_gemm<<<grdG, dim3(512), 0, stream>>>(aggh, out, Wf2, b2, out, (f16*)nullptr);
}

// Round 11
// 170.723 us; speedup vs baseline: 1.0161x; 1.0161x over previous
//
#include <hip/hip_runtime.h>

#define N_NODES 50000
#define N_EDGES 800000
#define DIM 128
#define NCHUNK 3125     // N_NODES / 16
#define SCAN_B 49       // ceil(50000 / 1024)
#define NBINS 782       // ceil(50000 / 64)
#define EPB 8192        // edges per binscat block
#define NSCAT 98        // ceil(800000 / 8192)
#define ZERO_INTS 50816 // 203,264 bytes / 4

typedef _Float16 f16;
typedef _Float16 f16x4 __attribute__((ext_vector_type(4)));
typedef _Float16 f16x8 __attribute__((ext_vector_type(8)));
typedef float    f32x4 __attribute__((ext_vector_type(4)));
typedef float    f32x8 __attribute__((ext_vector_type(8)));

__device__ inline f32x8 cvt8(f16x8 v) { return __builtin_convertvector(v, f32x8); }

__device__ inline int bucketof(int d) {
    if (d < 10) return 0;
    if (d < 13) return 1;
    if (d < 16) return 2;
    if (d < 19) return 3;
    if (d < 22) return 4;
    if (d < 26) return 5;
    if (d < 32) return 6;
    return 7;
}

// ---------------- zero the counter region ----------------

__global__ __launch_bounds__(256) void k_zero(int* __restrict__ p) {
    int i = blockIdx.x * 256 + threadIdx.x;
    if (i < ZERO_INTS) p[i] = 0;
}

// ---------------- fused: edge count (even blocks) + x->f16 (odd blocks) + W prep (tail blocks) ----------------

__global__ __launch_bounds__(256) void k_prep(const int* __restrict__ dst, int* __restrict__ deg,
                                              const float* __restrict__ x, f16* __restrict__ xh,
                                              const float* __restrict__ W1l, const float* __restrict__ W1r,
                                              const float* __restrict__ W2l, const float* __restrict__ W2r,
                                              f16* __restrict__ Wf1, f16* __restrict__ Wf2) {
    int b = blockIdx.x;
    if (b < 6250) {
        int idx = (b >> 1) * 256 + threadIdx.x;      // 0..799,999 exactly
        if ((b & 1) == 0) {
            atomicAdd(&deg[dst[idx]], 1);
        } else {
            const float4* xs = (const float4*)x;
            float4 v0 = xs[(size_t)idx * 2];
            float4 v1 = xs[(size_t)idx * 2 + 1];
            f16x8 o;
            o[0]=(f16)v0.x; o[1]=(f16)v0.y; o[2]=(f16)v0.z; o[3]=(f16)v0.w;
            o[4]=(f16)v1.x; o[5]=(f16)v1.y; o[6]=(f16)v1.z; o[7]=(f16)v1.w;
            *(f16x8*)(xh + (size_t)idx * 8) = o;
        }
    } else {
        int t = (b - 6250) * 256 + threadIdx.x;      // 0..8191
        int layer = t >> 12;
        int nt = (t >> 9) & 7;
        int kk = (t >> 6) & 7;
        int lane = t & 63;
        int r = lane & 15, g = lane >> 4;
        int n = nt * 16 + r;
        const float* Wl_ = layer ? W2l : W1l;
        const float* Wr_ = layer ? W2r : W1r;
        f16x8 frag;
#pragma unroll
        for (int j = 0; j < 8; ++j) {
            int k = kk * 32 + g * 4 + (j & 3) + ((j >> 2) << 4);
            float f = (k < 128) ? Wl_[n * 128 + k] : Wr_[n * 128 + (k - 128)];
            frag[j] = (f16)f;
        }
        f16* dstp = (layer ? Wf2 : Wf1) + ((size_t)((nt * 8 + kk) * 64 + lane)) * 8;
        *(f16x8*)dstp = frag;
    }
}

// ---------------- scan phase A ----------------

__global__ __launch_bounds__(1024) void k_scanA(const int* __restrict__ deg, int* __restrict__ rowptr,
                                                int* __restrict__ bsum, int* __restrict__ bcnt) {
    __shared__ int sm[1024];
    __shared__ int h[8];
    int t = threadIdx.x;
    if (t < 8) h[t] = 0;
    int i = blockIdx.x * 1024 + t;
    int v = (i < N_NODES) ? deg[i] : 0;
    int orig = v;
    sm[t] = v;
    __syncthreads();
    if (i < N_NODES) atomicAdd(&h[bucketof(orig)], 1);
    for (int off = 1; off < 1024; off <<= 1) {
        int u = (t >= off) ? sm[t - off] : 0;
        __syncthreads();
        sm[t] += u;
        __syncthreads();
    }
    if (i < N_NODES) rowptr[i] = sm[t] - orig;
    if (t == 1023) bsum[blockIdx.x] = sm[t];
    if (t < 8 && h[t] > 0) atomicAdd(&bcnt[t], h[t]);
}

// ---------------- scan phase B ----------------

__global__ __launch_bounds__(64) void k_scanB(const int* __restrict__ bsum, int* __restrict__ boff,
                                              int* __restrict__ rowptr, const int* __restrict__ bcnt,
                                              int* __restrict__ bbase) {
    int t = threadIdx.x;
    int orig = (t < SCAN_B) ? bsum[t] : 0;
    int v = orig;
    for (int off = 1; off < 64; off <<= 1) {
        int u = __shfl_up(v, off);
        if (t >= off) v += u;
    }
    if (t < SCAN_B) boff[t] = v - orig;
    if (t == 63) rowptr[N_NODES] = N_EDGES;
    if (t == 0) {
        int r = 0;
#pragma unroll
        for (int b = 0; b < 8; ++b) { bbase[b] = r; r += bcnt[b]; }
    }
}

// ---------------- scan phase C ----------------

__global__ __launch_bounds__(1024) void k_scanC(int* __restrict__ rowptr, const int* __restrict__ boff,
                                                const int* __restrict__ deg, const int* __restrict__ bbase,
                                                int* __restrict__ bcnt2, int* __restrict__ order) {
    __shared__ int h[8];
    __shared__ int hb[8];
    int t = threadIdx.x;
    if (t < 8) h[t] = 0;
    __syncthreads();
    int i = blockIdx.x * 1024 + t;
    int b = 0, rank = 0;
    bool act = (i < N_NODES);
    if (act) {
        rowptr[i] += boff[blockIdx.x];
        b = bucketof(deg[i]);
        rank = atomicAdd(&h[b], 1);
    }
    __syncthreads();
    if (t < 8) hb[t] = atomicAdd(&bcnt2[t], h[t]);
    __syncthreads();
    if (act) order[bbase[b] + hb[b] + rank] = i;
}

// ---------------- binned scatter pass A ----------------

__global__ __launch_bounds__(1024) void k_binscat(const int* __restrict__ src, const int* __restrict__ dst,
                                                  const int* __restrict__ rowptr, int* __restrict__ binfill,
                                                  int* __restrict__ pairs) {
    __shared__ int hist[NBINS];
    __shared__ int base[NBINS];
    int t = threadIdx.x;
    for (int i = t; i < NBINS; i += 1024) hist[i] = 0;
    __syncthreads();
    int e0 = blockIdx.x * EPB;
    int mybin[8], myrank[8], mypack[8];
#pragma unroll
    for (int j = 0; j < 8; ++j) {
        int e = e0 + j * 1024 + t;
        if (e < N_EDGES) {
            int d = dst[e];
            int bin = d >> 6;
            mybin[j] = bin;
            mypack[j] = (src[e] << 6) | (d & 63);
            myrank[j] = atomicAdd(&hist[bin], 1);
        } else {
            mybin[j] = -1;
        }
    }
    __syncthreads();
    for (int i = t; i < NBINS; i += 1024) base[i] = atomicAdd(&binfill[i], hist[i]);
    __syncthreads();
#pragma unroll
    for (int j = 0; j < 8; ++j) {
        if (mybin[j] >= 0) {
            int bin = mybin[j];
            pairs[rowptr[bin << 6] + base[bin] + myrank[j]] = mypack[j];
        }
    }
}

// ---------------- binned scatter pass B ----------------

__global__ __launch_bounds__(256) void k_binsolve(const int* __restrict__ pairs, const int* __restrict__ rowptr,
                                                  int* __restrict__ srt) {
    __shared__ int lfill[64];
    int bin = blockIdx.x;
    int nstart = bin << 6;
    int nend = min(N_NODES, nstart + 64);
    int t = threadIdx.x;
    if (t < 64) lfill[t] = (nstart + t < N_NODES) ? rowptr[nstart + t] : 0;
    __syncthreads();
    int estart = rowptr[nstart];
    int eend = rowptr[nend];
    for (int i = estart + t; i < eend; i += 256) {
        int p = pairs[i];
        int slot = atomicAdd(&lfill[p & 63], 1);
        srt[slot] = p >> 6;
    }
}

// ---------------- mean aggregation: 16-lane group per node, degree-binned order, unroll 8 ----------------

__global__ __launch_bounds__(256) void k_aggregate(const f16* __restrict__ X, const int* __restrict__ rowptr,
                                                   const int* __restrict__ srt, const int* __restrict__ order,
                                                   f16* __restrict__ out) {
    int gid = (blockIdx.x * 256 + threadIdx.x) >> 4;
    if (gid >= N_NODES) return;
    int w = order[gid];
    int lane = threadIdx.x & 15;
    const f16* __restrict__ base = X + lane * 8;
    int beg = rowptr[w], end = rowptr[w + 1];
    f32x8 A0 = {0.f,0.f,0.f,0.f,0.f,0.f,0.f,0.f};
    f32x8 A1 = A0, A2 = A0, A3 = A0;
    int e = beg;
    for (; e + 8 <= end; e += 8) {           // 8 rows in flight per node (32 per wave)
        int s0 = srt[e],     s1 = srt[e + 1], s2 = srt[e + 2], s3 = srt[e + 3];
        int s4 = srt[e + 4], s5 = srt[e + 5], s6 = srt[e + 6], s7 = srt[e + 7];
        f16x8 v0 = *(const f16x8*)(base + s0 * DIM);
        f16x8 v1 = *(const f16x8*)(base + s1 * DIM);
        f16x8 v2 = *(const f16x8*)(base + s2 * DIM);
        f16x8 v3 = *(const f16x8*)(base + s3 * DIM);
        f16x8 v4 = *(const f16x8*)(base + s4 * DIM);
        f16x8 v5 = *(const f16x8*)(base + s5 * DIM);
        f16x8 v6 = *(const f16x8*)(base + s6 * DIM);
        f16x8 v7 = *(const f16x8*)(base + s7 * DIM);
        A0 += cvt8(v0); A1 += cvt8(v1); A2 += cvt8(v2); A3 += cvt8(v3);
        A0 += cvt8(v4); A1 += cvt8(v5); A2 += cvt8(v6); A3 += cvt8(v7);
    }
    if (e + 4 <= end) {
        int s0 = srt[e], s1 = srt[e + 1], s2 = srt[e + 2], s3 = srt[e + 3];
        A0 += cvt8(*(const f16x8*)(base + s0 * DIM));
        A1 += cvt8(*(const f16x8*)(base + s1 * DIM));
        A2 += cvt8(*(const f16x8*)(base + s2 * DIM));
        A3 += cvt8(*(const f16x8*)(base + s3 * DIM));
        e += 4;
    }
    if (e < end)     A0 += cvt8(*(const f16x8*)(base + srt[e] * DIM));
    if (e + 1 < end) A1 += cvt8(*(const f16x8*)(base + srt[e + 1] * DIM));
    if (e + 2 < end) A2 += cvt8(*(const f16x8*)(base + srt[e + 2] * DIM));
    A0 = (A0 + A1) + (A2 + A3);
    float inv = 1.0f / fmaxf((float)(end - beg), 1.0f);
    f16x8 r;
#pragma unroll
    for (int j = 0; j < 8; ++j) r[j] = (f16)(A0[j] * inv);
    *(f16x8*)(out + (size_t)w * DIM + lane * 8) = r;
}

// ---------------- MFMA dual GEMM: C = relu([agg|self] @ Wcat^T + b), all-f16 A, 64 MFMA/chunk ----------------
// C (f32) and Cb (f16) each optional (null -> skip write).

__global__ __launch_bounds__(512) void k_gemm(const f16* __restrict__ Agg, const f16* __restrict__ Xs,
                                              const f16* __restrict__ Wf, const float* __restrict__ bias,
                                              float* __restrict__ C, f16* __restrict__ Cb) {
    __shared__ uint4 Bsm[4096];   // 64 KB: [nt][kk][lane] 16B fragments
    int t = threadIdx.x;
    const uint4* wsrc = (const uint4*)Wf;
#pragma unroll
    for (int i = 0; i < 8; ++i) Bsm[t + i * 512] = wsrc[t + i * 512];
    __syncthreads();

    int wave = t >> 6, lane = t & 63;
    int chunk = blockIdx.x * 8 + wave;
    if (chunk >= NCHUNK) return;
    int r = lane & 15, g = lane >> 4;
    size_t row = (size_t)chunk * 16 + r;

    f32x4 acc[8];
#pragma unroll
    for (int nt = 0; nt < 8; ++nt) acc[nt] = (f32x4){0.f, 0.f, 0.f, 0.f};

#pragma unroll
    for (int kk = 0; kk < 8; ++kk) {
        const f16* arow = (kk < 4 ? Agg : Xs) + row * DIM + (kk & 3) * 32 + g * 4;
        f16x4 q0 = *(const f16x4*)(arow);
        f16x4 q1 = *(const f16x4*)(arow + 16);
        f16x8 a = __builtin_shufflevector(q0, q1, 0, 1, 2, 3, 4, 5, 6, 7);
#pragma unroll
        for (int nt = 0; nt < 8; ++nt) {
            f16x8 b = *(const f16x8*)&Bsm[(nt * 8 + kk) * 64 + lane];
            acc[nt] = __builtin_amdgcn_mfma_f32_16x16x32_f16(a, b, acc[nt], 0, 0, 0);
        }
    }
    size_t rbase = (size_t)chunk * 16 + g * 4;
#pragma unroll
    for (int nt = 0; nt < 8; ++nt) {
        int colc = nt * 16 + r;
        float bv = bias[colc];
#pragma unroll
        for (int q = 0; q < 4; ++q) {
            float v = fmaxf(acc[nt][q] + bv, 0.f);
            size_t idx = (rbase + q) * DIM + colc;
            if (C)  C[idx] = v;
            if (Cb) Cb[idx] = (f16)v;
        }
    }
}

// ---------------- launch ----------------

extern "C" void kernel_launch(void* const* d_in, const int* in_sizes, int n_in,
                              void* d_out, int out_size, void* d_ws, size_t ws_size,
                              hipStream_t stream) {
    const float* x   = (const float*)d_in[0];
    const int*   ei  = (const int*)d_in[1];
    const float* W1l = (const float*)d_in[2];
    const float* b1  = (const float*)d_in[3];
    const float* W1r = (const float*)d_in[4];
    const float* W2l = (const float*)d_in[5];
    const float* b2  = (const float*)d_in[6];
    const float* W2r = (const float*)d_in[7];
    float* out = (float*)d_out;

    const int* src = ei;
    const int* dst = ei + N_EDGES;

    char* ws = (char*)d_ws;
    int*  deg     = (int*)(ws + 0);              // 200,000 B
    int*  bcnt    = (int*)(ws + 200064);         // 32 B
    int*  bcnt2   = (int*)(ws + 200096);         // 32 B
    int*  binfill = (int*)(ws + 200128);         // 3,128 B   (k_zero covers through here)
    int*  rowptr  = (int*)(ws + 203264);         // 200,004 B
    int*  srt     = (int*)(ws + 403328);         // 3,200,000 B
    f16*  xh      = (f16*)(ws + 3603328);        // 12.8 MB (x f16, then h f16 after layer 1)
    f16*  aggh    = (f16*)(ws + 16403328);       // 12.8 MB
    int*  pairs   = (int*)(ws + 16403328);       // 3.2 MB (overlaps aggh; dead before agg runs)
    f16*  Wf1     = (f16*)(ws + 29203328);       // 64 KB frag-order
    f16*  Wf2     = Wf1 + 32768;                 // 64 KB
    int*  bsum    = (int*)(ws + 29334400);       // 256 B
    int*  boff    = (int*)(ws + 29334656);       // 256 B
    int*  bbase   = (int*)(ws + 29334912);       // 64 B
    int*  order   = (int*)(ws + 29334976);       // 200,000 B

    dim3 blk(256);
    k_zero<<<dim3((ZERO_INTS + 255) / 256), blk, 0, stream>>>((int*)ws);
    k_prep<<<dim3(6282), blk, 0, stream>>>(dst, deg, x, xh, W1l, W1r, W2l, W2r, Wf1, Wf2);
    k_scanA<<<dim3(SCAN_B), dim3(1024), 0, stream>>>(deg, rowptr, bsum, bcnt);
    k_scanB<<<dim3(1), dim3(64), 0, stream>>>(bsum, boff, rowptr, bcnt, bbase);
    k_scanC<<<dim3(SCAN_B), dim3(1024), 0, stream>>>(rowptr, boff, deg, bbase, bcnt2, order);
    k_binscat<<<dim3(NSCAT), dim3(1024), 0, stream>>>(src, dst, rowptr, binfill, pairs);
    k_binsolve<<<dim3(NBINS), blk, 0, stream>>>(pairs, rowptr, srt);

    dim3 grdA(NCHUNK);                 // 50000 groups x 16 lanes = 3125 blocks
    dim3 grdG((NCHUNK + 7) / 8);

    // layer 1: h (f16 -> xh only) = relu(agg1 @ W1l^T + b1 + x @ W1r^T)   [self from xh f16]
    k_aggregate<<<grdA, blk, 0, stream>>>(xh, rowptr, srt, order, aggh);
    k_gemm<<<grdG, dim3(512), 0, stream>>>(aggh, xh, Wf1, b1, (float*)nullptr, xh);

    // layer 2: out (f32) = relu(agg2 @ W2l^T + b2 + h @ W2r^T)            [self from xh f16]
    k_aggregate<<<grdA, blk, 0, stream>>>(xh, rowptr, srt, order, aggh);
    k_gemm<<<grdG, dim3(512), 0, stream>>>(aggh, xh, Wf2, b2, out, (f16*)nullptr);
}